// Round 1
// 397.782 us; speedup vs baseline: 1.0047x; 1.0047x over previous
//
#include <hip/hip_runtime.h>

#define H 1024
#define V 50257
#define NBLK 3142  // ceil(V/16)

// ---------------- K1: gates + LSTM cell (all fp32) ----------------
// grid 1024, block 256. Block b owns hidden unit b. Wave w computes gate w:
// row = w*1024 + b of W_ih/W_hh (full 1024-length dot, one row per wave).
// vs previous version: 4x block parallelism (4 -> 16 waves/CU), 1/4 the
// serial rows + shfl chains per wave; identical HBM traffic (33.5 MB).
__global__ __launch_bounds__(256) void k_gates(
    const float* __restrict__ emb,
    const float* __restrict__ W_ih,
    const float* __restrict__ W_hh,
    const float* __restrict__ b_ih,
    const float* __restrict__ b_hh,
    const float* __restrict__ h0,
    const float* __restrict__ c0,
    const int* __restrict__ idx,
    float* __restrict__ hnew,
    float* __restrict__ out)
{
    __shared__ float g4[4];  // one pre-activation per gate
    const int tid  = threadIdx.x;
    const int wave = tid >> 6, lane = tid & 63;
    const int unit = blockIdx.x;           // hidden unit this block finishes
    const int row  = wave * H + unit;      // gate `wave` of unit `unit`
    const int xrow = idx[0];

    const float4* xp  = (const float4*)(emb + (size_t)xrow * H);
    const float4* hp  = (const float4*)h0;
    const float4* wip = (const float4*)(W_ih + (size_t)row * H);
    const float4* whp = (const float4*)(W_hh + (size_t)row * H);

    // lane's 16-elem slice: float4 at index lane + 64*j (coalesced 1KiB/instr)
    float acc = 0.f;
    #pragma unroll
    for (int j = 0; j < 4; j++) {
        float4 w = wip[lane + 64 * j];
        float4 x = xp [lane + 64 * j];
        acc += w.x * x.x + w.y * x.y + w.z * x.z + w.w * x.w;
    }
    #pragma unroll
    for (int j = 0; j < 4; j++) {
        float4 w = whp[lane + 64 * j];
        float4 h = hp [lane + 64 * j];
        acc += w.x * h.x + w.y * h.y + w.z * h.z + w.w * h.w;
    }
    #pragma unroll
    for (int off = 32; off; off >>= 1) acc += __shfl_down(acc, off, 64);
    if (lane == 0) g4[wave] = acc + b_ih[row] + b_hh[row];
    __syncthreads();

    if (tid == 0) {
        const float i = 1.f / (1.f + expf(-g4[0]));
        const float f = 1.f / (1.f + expf(-g4[1]));
        const float g = tanhf(g4[2]);
        const float o = 1.f / (1.f + expf(-g4[3]));
        const float c = f * c0[unit] + i * g;
        const float h = o * tanhf(c);
        hnew[unit]        = h;   // fp32 for K2
        out[V + unit]     = h;   // output 1: h_new
        out[V + H + unit] = c;   // output 2: c_new
    }
}

// ---------------- K2: vocab projection + per-block sum(exp) ----------------
// grid 3142, block 256. Block b: rows [16b, 16b+16); wave w: 4 rows.
// |logit| <= ~3 (h in (-1,1), W_out ~ N(0,0.02)), so max-free sumexp is safe.
__global__ __launch_bounds__(256) void k_logits(
    const float* __restrict__ W_out,
    const float* __restrict__ b_out,
    const float* __restrict__ hnew,
    float* __restrict__ out,
    float* __restrict__ partials)
{
    __shared__ float sl[16];
    const int tid  = threadIdx.x;
    const int wave = tid >> 6, lane = tid & 63;
    const int base = blockIdx.x * 16;

    const float4* hp = (const float4*)hnew;
    float4 hv[4];
    #pragma unroll
    for (int j = 0; j < 4; j++) hv[j] = hp[lane + 64 * j];

    #pragma unroll
    for (int k = 0; k < 4; k++) {
        const int v = base + wave * 4 + k;
        float logit = 0.f;
        if (v < V) {
            const float4* wp = (const float4*)(W_out + (size_t)v * H);
            float acc = 0.f;
            #pragma unroll
            for (int j = 0; j < 4; j++) {
                float4 w = wp[lane + 64 * j];
                acc += w.x * hv[j].x + w.y * hv[j].y + w.z * hv[j].z + w.w * hv[j].w;
            }
            #pragma unroll
            for (int off = 32; off; off >>= 1) acc += __shfl_down(acc, off, 64);
            logit = acc + b_out[v];
        }
        if (lane == 0) {
            sl[wave * 4 + k] = logit;
            if (v < V) out[v] = logit;  // fp32 logit, corrected in K3
        }
    }
    __syncthreads();
    if (tid == 0) {
        const int n = (V - base) < 16 ? (V - base) : 16;
        float s = 0.f;
        for (int k = 0; k < n; k++) s += expf(sl[k]);
        partials[blockIdx.x] = s;
    }
}

// ---------------- K3: redundant lse reduce + subtract ----------------
// grid 197, block 256. Every block reduces all 3142 partials (L2-resident,
// ~12.6 KB) -> lse, then applies out[v] -= lse. Removes a launch + global sync.
__global__ __launch_bounds__(256) void k_out(
    const float* __restrict__ partials, float* __restrict__ out)
{
    __shared__ float ss[256];
    const int tid = threadIdx.x;
    float s = 0.f;
    for (int i = tid; i < NBLK; i += 256) s += partials[i];
    ss[tid] = s;
    __syncthreads();
    #pragma unroll
    for (int off = 128; off; off >>= 1) {
        if (tid < off) ss[tid] += ss[tid + off];
        __syncthreads();
    }
    const float lse = logf(ss[0]);
    const int v = blockIdx.x * 256 + tid;
    if (v < V) out[v] -= lse;
}

extern "C" void kernel_launch(void* const* d_in, const int* in_sizes, int n_in,
                              void* d_out, int out_size, void* d_ws, size_t ws_size,
                              hipStream_t stream) {
    const float* emb   = (const float*)d_in[0];
    const float* W_ih  = (const float*)d_in[1];
    const float* W_hh  = (const float*)d_in[2];
    const float* b_ih  = (const float*)d_in[3];
    const float* b_hh  = (const float*)d_in[4];
    const float* W_out = (const float*)d_in[5];
    const float* b_out = (const float*)d_in[6];
    const float* h0    = (const float*)d_in[7];
    const float* c0    = (const float*)d_in[8];
    const int*   idx   = (const int*)d_in[9];

    float* out      = (float*)d_out;
    float* hnew     = (float*)d_ws;          // 1024 floats
    float* partials = hnew + 1024;           // 3142 floats (~16.7 KB total)

    k_gates <<<H, 256, 0, stream>>>(emb, W_ih, W_hh, b_ih, b_hh, h0, c0, idx,
                                    hnew, out);
    k_logits<<<NBLK, 256, 0, stream>>>(W_out, b_out, hnew, out, partials);
    k_out   <<<(V + 255) / 256, 256, 0, stream>>>(partials, out);
}